// Round 4
// baseline (135.456 us; speedup 1.0000x reference)
//
#include <hip/hip_runtime.h>

// Rowwise cosine similarity: out[r] = dot(a_r,b_r) * rsqrt(max(|a_r|^2,eps)) * rsqrt(max(|b_r|^2,eps))
// a, b: [16, 4096, 256] f32 contiguous -> 65536 rows of 256 floats.
//
// v5: v4 (nt loads, 8 rows/wave, 8 lanes/row) + FORCED load clustering.
//  r3 finding: nt loads dropped the kernel below the 41.5us fills (~35us est).
//  But VGPR_Count=32-36 across v2/v3/v4 proves the compiler never actually
//  kept 16 loads in flight -- it interleaved load->FMA->load, capping MLP at
//  ~4-6 outstanding. v5 pins the schedule with sched_barrier(0) fences:
//  all 16 nt dwordx4 loads MUST be emitted before the first FMA. VGPR rises
//  to ~130 (the tell), occupancy ~3-4 waves/SIMD, but each wave genuinely
//  holds 16KB outstanding. If this is null with VGPR confirmed high, the
//  residual ~14us over the 21.3us roofline is harness fill-writeback drain
//  contention (kernel-side unfixable) -> declare roofline.

#define D4         64          // float4s per row
#define EPS        1e-12f
#define LANES_ROW  8
#define ROWS_WAVE  8
#define F4_LANE    8
#define WAVES_BLK  4

typedef float f32x4 __attribute__((ext_vector_type(4)));

__global__ __launch_bounds__(256) void cosine_rows_kernel(
    const float* __restrict__ a,
    const float* __restrict__ b,
    float* __restrict__ out,
    int n_rows)
{
    const int lane = threadIdx.x & 63;
    const int wave = threadIdx.x >> 6;
    const int g    = lane >> 3;        // row index within this wave's batch
    const int s    = lane & 7;         // sublane within the row

    const int row = (blockIdx.x * WAVES_BLK + wave) * ROWS_WAVE + g;
    if (row >= n_rows) return;

    const f32x4* A = reinterpret_cast<const f32x4*>(a) + (size_t)row * D4 + s;
    const f32x4* B = reinterpret_cast<const f32x4*>(b) + (size_t)row * D4 + s;

    f32x4 av[F4_LANE], bv[F4_LANE];

    // ---- load cluster: all 16 nt dwordx4 issued back-to-back ----
    __builtin_amdgcn_sched_barrier(0);
    #pragma unroll
    for (int k = 0; k < F4_LANE; ++k) {
        av[k] = __builtin_nontemporal_load(A + k * LANES_ROW);
        bv[k] = __builtin_nontemporal_load(B + k * LANES_ROW);
    }
    __builtin_amdgcn_sched_barrier(0);
    // ---- compute cluster: consumes in issue order (vmcnt counts down) ----

    float sa = 0.f, sb = 0.f, sab = 0.f;
    #pragma unroll
    for (int k = 0; k < F4_LANE; ++k) {
        f32x4 x = av[k], y = bv[k];
        sa  += x.x * x.x + x.y * x.y + x.z * x.z + x.w * x.w;
        sb  += y.x * y.x + y.y * y.y + y.z * y.z + y.w * y.w;
        sab += x.x * y.x + x.y * y.y + x.z * y.z + x.w * y.w;
    }

    // 3-step butterfly within the 8-lane group (groups are xor-aligned).
    #pragma unroll
    for (int off = 1; off < LANES_ROW; off <<= 1) {
        sa  += __shfl_xor(sa,  off, 64);
        sb  += __shfl_xor(sb,  off, 64);
        sab += __shfl_xor(sab, off, 64);
    }

    if (s == 0) {
        out[row] = sab * rsqrtf(fmaxf(sa, EPS)) * rsqrtf(fmaxf(sb, EPS));
    }
}

extern "C" void kernel_launch(void* const* d_in, const int* in_sizes, int n_in,
                              void* d_out, int out_size, void* d_ws, size_t ws_size,
                              hipStream_t stream)
{
    const float* a = (const float*)d_in[0];
    const float* b = (const float*)d_in[1];
    float* out = (float*)d_out;

    const int n_rows = out_size;                        // 16 * 4096 = 65536
    const int rows_per_block = WAVES_BLK * ROWS_WAVE;   // 32
    const int grid = (n_rows + rows_per_block - 1) / rows_per_block;

    cosine_rows_kernel<<<grid, 256, 0, stream>>>(a, b, out, n_rows);
}